// Round 2
// baseline (43.186 us; speedup 1.0000x reference)
//
#include <hip/hip_runtime.h>

#define N 4096
#define M 1024
#define D 64
#define MT 16                             // m-values per thread
#define SPLITS 16                         // N-chunks
#define ROWS_PER_BLOCK (N / SPLITS)       // 256
#define ROWS_PER_WAVE  (ROWS_PER_BLOCK/4) // 64
#define SITES (M * D)                     // 65536

// K1: partial min over an N-chunk for a 16-m tile, with the z_masked/z_copy
// stores fused in (they hide under the VALU loop). grid = 64 m-tiles * 16
// splits = 1024 blocks (4 blocks/CU), 256 threads. lane = d.
// Trick: min_n (z-e)^2 = min_n (z^2 - 2ez) + e^2  -> 2.06 VALU ops/site.
// pout stores the t = z^2-2ez partial mins; e^2 is added in K2.
__global__ __launch_bounds__(256) void k_minpart(const float* __restrict__ z,
                                                 const float* __restrict__ e,
                                                 const int* __restrict__ idx,
                                                 float* __restrict__ pout,
                                                 float* __restrict__ out,
                                                 int* __restrict__ counter) {
    const int bid = blockIdx.x;
    if (bid == 0 && threadIdx.x == 0) *counter = 0;   // reset for K2, every call

    // fused elementwise outputs: 256 elements per block
    {
        const int i = bid * 256 + (int)threadIdx.x;
        const float zv = z[i];
        const int row = i >> 6, dd = i & 63;
        out[1 + i] = (dd < idx[row]) ? zv : 0.0f;   // z_masked
        out[1 + N * D + i] = zv;                    // z_copy
    }

    const int mt   = bid & 63;    // m-tile
    const int s    = bid >> 6;    // split
    const int lane = threadIdx.x & 63;
    const int w    = threadIdx.x >> 6;
    const int m0   = mt * MT;

    float n2e[MT];
#pragma unroll
    for (int j = 0; j < MT; ++j) n2e[j] = -2.0f * e[(m0 + j) * D + lane];

    float acc[MT];
#pragma unroll
    for (int j = 0; j < MT; ++j) acc[j] = 3.4e38f;

    const float* zp = z + (s * ROWS_PER_BLOCK + w * ROWS_PER_WAVE) * D + lane;
#pragma unroll 4
    for (int r = 0; r < ROWS_PER_WAVE; ++r) {
        const float zv = zp[r * D];
        const float z2 = zv * zv;
#pragma unroll
        for (int j = 0; j < MT; ++j)
            acc[j] = fminf(acc[j], fmaf(n2e[j], zv, z2));
    }

    __shared__ float lds[4][MT * 64];
#pragma unroll
    for (int j = 0; j < MT; ++j) lds[w][j * 64 + lane] = acc[j];
    __syncthreads();
    for (int p = threadIdx.x; p < MT * 64; p += 256) {
        const float v = fminf(fminf(lds[0][p], lds[1][p]),
                              fminf(lds[2][p], lds[3][p]));
        pout[s * SITES + m0 * 64 + p] = v;   // coalesced
    }
}

// K2: min over the 16 splits + e^2, sum, and deterministic grid-level finish
// via last-block-done (integer counter; final 64-term sum in fixed order).
__global__ __launch_bounds__(256) void k_minsum(const float* __restrict__ pout,
                                                const float* __restrict__ e,
                                                float* __restrict__ bsums,
                                                int* __restrict__ counter,
                                                float* __restrict__ out) {
    const int t = blockIdx.x * 256 + (int)threadIdx.x;  // 16384 threads
    float local = 0.0f;
#pragma unroll
    for (int k = 0; k < 4; ++k) {
        const int site = t + k * 16384;
        float v = 3.4e38f;
#pragma unroll
        for (int si = 0; si < SPLITS; ++si)
            v = fminf(v, pout[si * SITES + site]);
        const float ev = e[site];
        local += v + ev * ev;
    }
#pragma unroll
    for (int off = 32; off > 0; off >>= 1)
        local += __shfl_down(local, off, 64);
    __shared__ float wsum[4];
    const int lane = threadIdx.x & 63, w = threadIdx.x >> 6;
    if (lane == 0) wsum[w] = local;
    __syncthreads();
    if (threadIdx.x == 0) {
        // publish block sum at device coherence point
        atomicExch(&bsums[blockIdx.x], (wsum[0] + wsum[1]) + (wsum[2] + wsum[3]));
        __threadfence();
        const int prev = atomicAdd(counter, 1);
        if (prev == 63) {                 // exactly one block; fixed-order sum
            __threadfence();
            float s = 0.0f;
            for (int b = 0; b < 64; ++b)
                s += atomicAdd(&bsums[b], 0.0f);   // coherent read (returns old)
            out[0] = s * (1.0f / SITES);
        }
    }
}

extern "C" void kernel_launch(void* const* d_in, const int* in_sizes, int n_in,
                              void* d_out, int out_size, void* d_ws, size_t ws_size,
                              hipStream_t stream) {
    const float* z   = (const float*)d_in[0];
    const float* e   = (const float*)d_in[1];
    const int*   idx = (const int*)d_in[2];
    float* out = (float*)d_out;

    float* pout    = (float*)d_ws;                       // 4 MB partials
    float* bsums   = (float*)d_ws + SPLITS * SITES;      // 64 floats
    int*   counter = (int*)(bsums + 64);

    k_minpart<<<64 * SPLITS, 256, 0, stream>>>(z, e, idx, pout, out, counter);
    k_minsum<<<64, 256, 0, stream>>>(pout, e, bsums, counter, out);
}

// Round 3
// 23.836 us; speedup vs baseline: 1.8118x; 1.8118x over previous
//
#include <hip/hip_runtime.h>

#define N 4096
#define M 1024
#define D 64
#define MT 16                             // m-values per thread
#define SPLITS 16                         // N-chunks
#define ROWS_PER_BLOCK (N / SPLITS)       // 256
#define ROWS_PER_WAVE  (ROWS_PER_BLOCK/4) // 64
#define SITES (M * D)                     // 65536

// K1: partial min over an N-chunk for a 16-m tile, with the z_masked/z_copy
// stores fused in. grid = 64 m-tiles * 16 splits = 1024 blocks, 256 threads.
// lane = d. Trick: min_n (z-e)^2 = min_n (z^2 - 2ez) + e^2 -> ~2 ops/site.
// pout holds partial mins of t = z^2 - 2ez; e^2 added in K2.
__global__ __launch_bounds__(256) void k_minpart(const float* __restrict__ z,
                                                 const float* __restrict__ e,
                                                 const int* __restrict__ idx,
                                                 float* __restrict__ pout,
                                                 float* __restrict__ out,
                                                 int* __restrict__ counter) {
    const int bid = blockIdx.x;
    if (bid == 0 && threadIdx.x == 0) *counter = 0;   // reset for K2, every call

    // fused elementwise outputs: 256 elements per block
    {
        const int i = bid * 256 + (int)threadIdx.x;
        const float zv = z[i];
        const int row = i >> 6, dd = i & 63;
        out[1 + i] = (dd < idx[row]) ? zv : 0.0f;   // z_masked
        out[1 + N * D + i] = zv;                    // z_copy
    }

    const int mt   = bid & 63;    // m-tile
    const int s    = bid >> 6;    // split
    const int lane = threadIdx.x & 63;
    const int w    = threadIdx.x >> 6;
    const int m0   = mt * MT;

    float n2e[MT];
#pragma unroll
    for (int j = 0; j < MT; ++j) n2e[j] = -2.0f * e[(m0 + j) * D + lane];

    float acc[MT];
#pragma unroll
    for (int j = 0; j < MT; ++j) acc[j] = 3.4e38f;

    const float* zp = z + (s * ROWS_PER_BLOCK + w * ROWS_PER_WAVE) * D + lane;
#pragma unroll 4
    for (int r = 0; r < ROWS_PER_WAVE; ++r) {
        const float zv = zp[r * D];
        const float z2 = zv * zv;
#pragma unroll
        for (int j = 0; j < MT; ++j)
            acc[j] = fminf(acc[j], fmaf(n2e[j], zv, z2));
    }

    __shared__ float lds[4][MT * 64];
#pragma unroll
    for (int j = 0; j < MT; ++j) lds[w][j * 64 + lane] = acc[j];
    __syncthreads();
    for (int p = threadIdx.x; p < MT * 64; p += 256) {
        const float v = fminf(fminf(lds[0][p], lds[1][p]),
                              fminf(lds[2][p], lds[3][p]));
        pout[s * SITES + m0 * 64 + p] = v;   // coalesced
    }
}

// K2: min over the 16 splits + e^2, sum, then deterministic grid-level finish.
// Last-block-done; the final 64-term sum is read by 64 PARALLEL lanes (one
// coherent atomic read each) and reduced in a fixed-order shuffle tree.
__global__ __launch_bounds__(256) void k_minsum(const float* __restrict__ pout,
                                                const float* __restrict__ e,
                                                float* __restrict__ bsums,
                                                int* __restrict__ counter,
                                                float* __restrict__ out) {
    const int t = blockIdx.x * 256 + (int)threadIdx.x;  // 16384 threads
    float local = 0.0f;
#pragma unroll
    for (int k = 0; k < 4; ++k) {
        const int site = t + k * 16384;
        float v = 3.4e38f;
#pragma unroll
        for (int si = 0; si < SPLITS; ++si)
            v = fminf(v, pout[si * SITES + site]);
        const float ev = e[site];
        local += v + ev * ev;
    }
#pragma unroll
    for (int off = 32; off > 0; off >>= 1)
        local += __shfl_down(local, off, 64);
    __shared__ float wsum[4];
    __shared__ int is_last;
    const int lane = threadIdx.x & 63, w = threadIdx.x >> 6;
    if (lane == 0) wsum[w] = local;
    __syncthreads();
    if (threadIdx.x == 0) {
        // publish block sum at device coherence point
        atomicExch(&bsums[blockIdx.x], (wsum[0] + wsum[1]) + (wsum[2] + wsum[3]));
        __threadfence();
        is_last = (atomicAdd(counter, 1) == 63);
    }
    __syncthreads();
    if (is_last && threadIdx.x < 64) {
        __threadfence();
        // 64 parallel coherent reads (one per lane), fixed-order tree sum
        float v = atomicAdd(&bsums[threadIdx.x], 0.0f);
#pragma unroll
        for (int off = 32; off > 0; off >>= 1)
            v += __shfl_down(v, off, 64);
        if (threadIdx.x == 0) out[0] = v * (1.0f / SITES);
    }
}

extern "C" void kernel_launch(void* const* d_in, const int* in_sizes, int n_in,
                              void* d_out, int out_size, void* d_ws, size_t ws_size,
                              hipStream_t stream) {
    const float* z   = (const float*)d_in[0];
    const float* e   = (const float*)d_in[1];
    const int*   idx = (const int*)d_in[2];
    float* out = (float*)d_out;

    float* pout    = (float*)d_ws;                       // 4 MB partials
    float* bsums   = (float*)d_ws + SPLITS * SITES;      // 64 floats
    int*   counter = (int*)(bsums + 64);

    k_minpart<<<64 * SPLITS, 256, 0, stream>>>(z, e, idx, pout, out, counter);
    k_minsum<<<64, 256, 0, stream>>>(pout, e, bsums, counter, out);
}